// Round 8
// baseline (913.004 us; speedup 1.0000x reference)
//
#include <hip/hip_runtime.h>
#include <hip/hip_cooperative_groups.h>
#include <hip/hip_fp16.h>
#include <stdint.h>

namespace cg = cooperative_groups;

typedef _Float16 f16;
typedef _Float16 f16x8 __attribute__((ext_vector_type(8)));
typedef float f32x4 __attribute__((ext_vector_type(4)));

#define NROWS 262144
#define MROWS 16
#define TPB   512            // 8 waves
#define GPB   64
#define NBLK  256            // 1 block/CU -> cooperative co-residency guaranteed
#define THR   0.9921875f

// ws (f16 element offsets)
#define WS_TABT 0            // [768 u][192 k]
#define WS_W2FS 147456       // [8 w][16 j][96 k]  = 12288
#define WS_W2VA 159744       // [8 w][16 j][96 k]  = 12288
#define PREP_N  172032

// LDS map (bytes)
//  f32 counts [4 tb][16 row][196]      @0      (50176)  zero/scatter/convert-read
//  f16 counts [4 tb][16 row][200]      @0      (25600)  convert-write/gemm (in-place)
//  feat       [8 w][16 row][136 f16]   @25600  (34816)  row: a32|b32|absh16|absr16|hr16|z16 (+8 pad)
//  exch f32   [2 buf][512]             @60416  (4096)
//  prodrow    f32 [4][16]              @64512  (256)
#define FEAT_B  25600
#define EXCH_B  60416
#define PROW_B  64512
#define SMEM_SZ 64768

__device__ __forceinline__ f16x8 bc8(uint4 u) {
  union { uint4 u; f16x8 h; } x; x.u = u; return x.h;
}
__device__ __forceinline__ float clampv(float x) {
  return fminf(fmaxf(x, -THR), THR);
}
__device__ __forceinline__ uint32_t pk2(float a, float b) {
  union { __half2 h; uint32_t u; } c; c.h = __floats2half2_rn(a, b); return c.u;
}
__device__ __forceinline__ uint32_t pkrtz(float a, float b) {
  union { decltype(__builtin_amdgcn_cvt_pkrtz(0.f, 0.f)) h; uint32_t u; } c;
  c.h = __builtin_amdgcn_cvt_pkrtz(a, b);
  return c.u;
}
__device__ __forceinline__ uint4 mul8(uint4 a, uint4 b) {
  union { uint4 u; f16x8 h; } x, y, r;
  x.u = a; y.u = b; r.h = x.h * y.h; return r.u;
}
__device__ __forceinline__ uint4 abs8(uint4 a) {
  return make_uint4(a.x & 0x7FFF7FFFu, a.y & 0x7FFF7FFFu,
                    a.z & 0x7FFF7FFFu, a.w & 0x7FFF7FFFu);
}
__device__ __forceinline__ f32x4 mf(f32x4 acc, uint4 a, uint4 b) {
  return __builtin_amdgcn_mfma_f32_16x16x32_f16(bc8(a), bc8(b), acc, 0, 0, 0);
}

__global__ __launch_bounds__(TPB, 2)
void rengar_all(const int* __restrict__ pst_idx, const float* __restrict__ color_sign,
                const float* __restrict__ sob_sign, const float* __restrict__ wtm,
                const float* __restrict__ tempo_w, const float* __restrict__ fs_b,
                const float* __restrict__ out_va_w, const float* __restrict__ out_fsxva_w,
                const float* __restrict__ emb_fs, const float* __restrict__ emb_va,
                const float* __restrict__ emb_ha, const float* __restrict__ emb_ra,
                const float* __restrict__ fs_w,   const float* __restrict__ absva_w,
                const float* __restrict__ absha_w,const float* __restrict__ absra_w,
                const float* __restrict__ va_w,   const float* __restrict__ fsxva_w,
                const float* __restrict__ haxra_w,
                f16* __restrict__ ws, float* __restrict__ out) {
  __shared__ __align__(16) char smem[SMEM_SZ];

  const int tid  = threadIdx.x;
  const int lane = tid & 63;
  const int w    = tid >> 6;          // wave 0..7
  const int l15  = lane & 15;
  const int q    = lane >> 4;

  // ================= phase 0: prepack whole grid, then grid sync ============
  #pragma unroll
  for (int it = 0; it < 2; ++it) {
    int gid = it * (NBLK * TPB) + blockIdx.x * TPB + tid;
    if (gid < 147456) {                       // tabT[u][k] = table[k][u] as f16
      int k = gid / 768, u = gid - k * 768;
      float v = 0.f;
      if (k < 185) {
        if      (u < 256) v = emb_fs[k * 256 + u];
        else if (u < 512) v = emb_va[k * 256 + (u - 256)];
        else if (u < 640) v = emb_ha[k * 128 + (u - 512)];
        else              v = emb_ra[k * 128 + (u - 640)];
      }
      ws[u * 192 + k] = (f16)v;
    } else if (gid < WS_W2VA) {               // w2fs[w][j][96]
      int g2 = gid - WS_W2FS;
      int wv = g2 / 1536, rem = g2 - wv * 1536, j = rem / 96, k = rem - j * 96;
      float v = (k < 32) ? fs_w[j * 256 + 32 * wv + k]
              : (k < 64) ? absva_w[j * 256 + 32 * wv + (k - 32)]
              : (k < 80) ? absha_w[j * 128 + 16 * wv + (k - 64)]
                         : absra_w[j * 128 + 16 * wv + (k - 80)];
      ws[gid] = (f16)v;
    } else if (gid < PREP_N) {                // w2va[w][j][96]
      int g2 = gid - WS_W2VA;
      int wv = g2 / 1536, rem = g2 - wv * 1536, j = rem / 96, k = rem - j * 96;
      float v = (k < 32) ? va_w[j * 256 + 32 * wv + k]
              : (k < 64) ? fsxva_w[j * 256 + 32 * wv + (k - 32)]
              : (k < 80) ? haxra_w[j * 128 + 16 * wv + (k - 64)]
                         : 0.f;
      ws[gid] = (f16)v;
    }
  }
  cg::this_grid().sync();

  // ---- hoist fs/va layer-1 A-fragments (register-resident, 96 VGPR) ----
  uint4 afr[24];                      // tiles: fs{32w,32w+16}, va{256+32w,272+32w}
  {
    const int ub[4] = {32 * w, 32 * w + 16, 256 + 32 * w, 272 + 32 * w};
    #pragma unroll
    for (int t = 0; t < 4; ++t) {
      const f16* p = ws + (size_t)(ub[t] + l15) * 192 + q * 8;
      #pragma unroll
      for (int ks = 0; ks < 6; ++ks) afr[t * 6 + ks] = *(const uint4*)(p + ks * 32);
    }
  }
  // ---- layer-2 per-wave A slices (24 VGPR) ----
  uint4 a2f[3], a2v[3];
  {
    const f16* wf = ws + WS_W2FS + w * 1536 + l15 * 96 + q * 8;
    const f16* wv2 = ws + WS_W2VA + w * 1536 + l15 * 96 + q * 8;
    #pragma unroll
    for (int ks = 0; ks < 3; ++ks) {
      a2f[ks] = *(const uint4*)(wf + ks * 32);
      a2v[ks] = *(const uint4*)(wv2 + ks * 32);
    }
  }
  float4 tw0 = *(const float4*)(tempo_w + 32 * w + q * 4);
  float4 tw1 = *(const float4*)(tempo_w + 32 * w + 16 + q * 4);

  float bj = 0.f, w1j = 0.f, w2j = 0.f;
  if (tid < 256) {
    bj  = fs_b[tid >> 4];
    w1j = out_va_w[tid >> 4];
    w2j = out_fsxva_w[tid >> 4];
  }

  const int ebase = blockIdx.x * GPB * 512;
  int   v0 = pst_idx[ebase + tid];
  float c0 = color_sign[ebase + tid];
  float s0 = sob_sign[ebase + tid];
  float wtr = wtm[blockIdx.x * GPB * MROWS + l15];

  char* fb = smem + FEAT_B + w * 4352;   // wave-private feature slice

  #pragma unroll 1
  for (int g = 0; g < GPB; ++g) {
    const int r0  = (blockIdx.x * GPB + g) * MROWS;
    const int buf = g & 1;

    // ---- zero f32 count grid (3136 uint4) + this group's exch (128 uint4)
    {
      uint4 z = make_uint4(0, 0, 0, 0);
      #pragma unroll
      for (int it = 0; it < 7; ++it) {
        int i = tid + 512 * it;
        if (i < 3264) {
          char* d = (i < 3136) ? smem + i * 16
                               : smem + EXCH_B + buf * 2048 + (i - 3136) * 16;
          *(uint4*)d = z;
        }
      }
    }
    __syncthreads();                                   // b1

    // store previous group's output
    if (g > 0 && tid < 16) {
      const float* pr = (const float*)(smem + PROW_B);
      out[r0 - MROWS + tid] = pr[tid] + pr[16 + tid] + pr[32 + tid] + pr[48 + tid];
    }

    // ---- scatter all 4 tables (ds_add_f32)
    {
      float* cnt = (float*)smem;
      int idx = (tid >> 5) * 196 + v0;
      atomicAdd(cnt + idx,        1.f);
      atomicAdd(cnt + idx + 3136, c0);
      atomicAdd(cnt + idx + 6272, s0);
      atomicAdd(cnt + idx + 9408, c0 * s0);
    }
    // prefetch next group's inputs
    float nwt = wtr;
    if (g + 1 < GPB) {
      int nb = ebase + (g + 1) * 512;
      v0 = pst_idx[nb + tid];
      c0 = color_sign[nb + tid];
      s0 = sob_sign[nb + tid];
      nwt = wtm[r0 + MROWS + l15];
    }
    __syncthreads();                                   // b2

    // ---- convert f32 -> f16 in place: read 24 floats/thread
    float4 cv[6];
    {
      const float* src = (const float*)smem + (tid >> 3) * 196 + (tid & 7) * 24;
      #pragma unroll
      for (int i = 0; i < 6; ++i) cv[i] = *(const float4*)(src + i * 4);
    }
    __syncthreads();                                   // b3
    {
      char* dst = smem + (tid >> 3) * 400 + (tid & 7) * 48;
      uint4 w0 = make_uint4(pkrtz(cv[0].x, cv[0].y), pkrtz(cv[0].z, cv[0].w),
                            pkrtz(cv[1].x, cv[1].y), pkrtz(cv[1].z, cv[1].w));
      uint4 w1 = make_uint4(pkrtz(cv[2].x, cv[2].y), pkrtz(cv[2].z, cv[2].w),
                            pkrtz(cv[3].x, cv[3].y), pkrtz(cv[3].z, cv[3].w));
      uint4 w2 = make_uint4(pkrtz(cv[4].x, cv[4].y), pkrtz(cv[4].z, cv[4].w),
                            pkrtz(cv[5].x, cv[5].y), pkrtz(cv[5].z, cv[5].w));
      *(uint4*)dst        = w0;
      *(uint4*)(dst + 16) = w1;
      *(uint4*)(dst + 32) = w2;
    }
    __syncthreads();                                   // b4

    // ---- layer-1 GEMM: fs/va A in regs, ha/ra streamed from L2
    f32x4 accA0 = {0,0,0,0}, accA1 = {0,0,0,0}, accB0 = {0,0,0,0},
          accB1 = {0,0,0,0}, accH  = {0,0,0,0}, accR  = {0,0,0,0};
    {
      uint4 afrE[6], afrF[6];
      const f16* pE = ws + (size_t)(512 + 16 * w + l15) * 192 + q * 8;
      const f16* pF = ws + (size_t)(640 + 16 * w + l15) * 192 + q * 8;
      #pragma unroll
      for (int ks = 0; ks < 6; ++ks) {
        afrE[ks] = *(const uint4*)(pE + ks * 32);
        afrF[ks] = *(const uint4*)(pF + ks * 32);
      }
      const char* fg = smem;        // f16 count grid [4][16][200]
      uint4 bfr[6];
      #pragma unroll
      for (int ks = 0; ks < 6; ++ks)
        bfr[ks] = *(const uint4*)(fg + l15 * 400 + (ks * 32 + q * 8) * 2);
      #pragma unroll
      for (int ks = 0; ks < 6; ++ks) {
        accA0 = mf(accA0, afr[ks],     bfr[ks]);
        accA1 = mf(accA1, afr[6 + ks], bfr[ks]);
      }
      #pragma unroll
      for (int ks = 0; ks < 6; ++ks)
        bfr[ks] = *(const uint4*)(fg + 6400 + l15 * 400 + (ks * 32 + q * 8) * 2);
      #pragma unroll
      for (int ks = 0; ks < 6; ++ks) {
        accB0 = mf(accB0, afr[12 + ks], bfr[ks]);
        accB1 = mf(accB1, afr[18 + ks], bfr[ks]);
      }
      #pragma unroll
      for (int ks = 0; ks < 6; ++ks)
        bfr[ks] = *(const uint4*)(fg + 12800 + l15 * 400 + (ks * 32 + q * 8) * 2);
      #pragma unroll
      for (int ks = 0; ks < 6; ++ks) accH = mf(accH, afrE[ks], bfr[ks]);
      #pragma unroll
      for (int ks = 0; ks < 6; ++ks)
        bfr[ks] = *(const uint4*)(fg + 19200 + l15 * 400 + (ks * 32 + q * 8) * 2);
      #pragma unroll
      for (int ks = 0; ks < 6; ++ks) accR = mf(accR, afrF[ks], bfr[ks]);
    }

    // ---- epilogue: clamp, tempo, derived products; write wave-local slice
    {
      float twa[4] = {tw0.x, tw0.y, tw0.z, tw0.w};
      float twb[4] = {tw1.x, tw1.y, tw1.z, tw1.w};
      float a0[4], a1[4], b0[4], b1[4], hh[4], rr[4];
      #pragma unroll
      for (int r = 0; r < 4; ++r) {
        a0[r] = clampv(accA0[r]);
        a1[r] = clampv(accA1[r]);
        b0[r] = clampv(accB0[r] + wtr * twa[r]);
        b1[r] = clampv(accB1[r] + wtr * twb[r]);
        hh[r] = clampv(accH[r]);
        rr[r] = clampv(accR[r]);
      }
      int rb = l15 * 272 + q * 8;
      *(uint2*)(fb + rb)       = make_uint2(pk2(a0[0], a0[1]), pk2(a0[2], a0[3]));
      *(uint2*)(fb + rb + 32)  = make_uint2(pk2(a1[0], a1[1]), pk2(a1[2], a1[3]));
      *(uint2*)(fb + rb + 64)  = make_uint2(pk2(b0[0], b0[1]), pk2(b0[2], b0[3]));
      *(uint2*)(fb + rb + 96)  = make_uint2(pk2(b1[0], b1[1]), pk2(b1[2], b1[3]));
      *(uint2*)(fb + rb + 128) = make_uint2(pk2(fabsf(hh[0]), fabsf(hh[1])),
                                            pk2(fabsf(hh[2]), fabsf(hh[3])));
      *(uint2*)(fb + rb + 160) = make_uint2(pk2(fabsf(rr[0]), fabsf(rr[1])),
                                            pk2(fabsf(rr[2]), fabsf(rr[3])));
      *(uint2*)(fb + rb + 192) = make_uint2(pk2(hh[0] * rr[0], hh[1] * rr[1]),
                                            pk2(hh[2] * rr[2], hh[3] * rr[3]));
      *(uint2*)(fb + rb + 224) = make_uint2(0u, 0u);
    }

    // ---- layer-2 (wave-local): read back in B layout, derive |b|, ab in regs
    f32x4 accf = {0,0,0,0}, accv = {0,0,0,0};
    {
      uint4 raw0 = *(const uint4*)(fb + l15 * 272 +   0 + q * 16);
      uint4 raw1 = *(const uint4*)(fb + l15 * 272 +  64 + q * 16);
      uint4 raw2 = *(const uint4*)(fb + l15 * 272 + 128 + q * 16);
      uint4 raw3 = *(const uint4*)(fb + l15 * 272 + 192 + q * 16);
      accf = mf(accf, a2f[0], raw0);
      accf = mf(accf, a2f[1], abs8(raw1));
      accf = mf(accf, a2f[2], raw2);
      accv = mf(accv, a2v[0], raw1);
      accv = mf(accv, a2v[1], mul8(raw0, raw1));
      accv = mf(accv, a2v[2], raw3);
    }

    // ---- merge split-K partials
    {
      float* ex = (float*)(smem + EXCH_B + buf * 2048);
      #pragma unroll
      for (int r = 0; r < 4; ++r) {
        int idx = (q * 4 + r) * 16 + l15;
        atomicAdd(ex + idx,       accf[r]);
        atomicAdd(ex + idx + 256, accv[r]);
      }
    }
    __syncthreads();                                   // b5

    // ---- reduce to prodrow
    if (tid < 256) {
      const float* ex = (const float*)(smem + EXCH_B + buf * 2048);
      float f = clampv(ex[tid] + bj);
      float v = clampv(ex[256 + tid]);
      float o = v * w1j + f * v * w2j;
      o += __shfl_xor(o, 16, 64);
      o += __shfl_xor(o, 32, 64);
      if (lane < 16)
        ((float*)(smem + PROW_B))[(tid >> 6) * 16 + lane] = o;
    }
    wtr = nwt;
  }

  __syncthreads();
  if (tid < 16) {
    const float* pr = (const float*)(smem + PROW_B);
    int r0last = (blockIdx.x * GPB + GPB - 1) * MROWS;
    out[r0last + tid] = pr[tid] + pr[16 + tid] + pr[32 + tid] + pr[48 + tid];
  }
}

extern "C" void kernel_launch(void* const* d_in, const int* in_sizes, int n_in,
                              void* d_out, int out_size, void* d_ws, size_t ws_size,
                              hipStream_t stream) {
  const int*   pst_idx     = (const int*)  d_in[0];
  const float* color_sign  = (const float*)d_in[1];
  const float* sob_sign    = (const float*)d_in[2];
  const float* wtm         = (const float*)d_in[3];
  const float* emb_fs      = (const float*)d_in[4];
  const float* emb_va      = (const float*)d_in[5];
  const float* emb_ha      = (const float*)d_in[6];
  const float* emb_ra      = (const float*)d_in[7];
  const float* tempo_w     = (const float*)d_in[8];
  const float* fs_w        = (const float*)d_in[9];
  const float* fs_b        = (const float*)d_in[10];
  const float* absva_w     = (const float*)d_in[11];
  const float* absha_w     = (const float*)d_in[12];
  const float* absra_w     = (const float*)d_in[13];
  const float* va_w        = (const float*)d_in[14];
  const float* fsxva_w     = (const float*)d_in[15];
  const float* haxra_w     = (const float*)d_in[16];
  const float* out_va_w    = (const float*)d_in[17];
  const float* out_fsxva_w = (const float*)d_in[18];
  float* out = (float*)d_out;
  f16* ws = (f16*)d_ws;

  void* args[] = {
    (void*)&pst_idx, (void*)&color_sign, (void*)&sob_sign, (void*)&wtm,
    (void*)&tempo_w, (void*)&fs_b, (void*)&out_va_w, (void*)&out_fsxva_w,
    (void*)&emb_fs, (void*)&emb_va, (void*)&emb_ha, (void*)&emb_ra,
    (void*)&fs_w, (void*)&absva_w, (void*)&absha_w, (void*)&absra_w,
    (void*)&va_w, (void*)&fsxva_w, (void*)&haxra_w,
    (void*)&ws, (void*)&out
  };
  hipLaunchCooperativeKernel((const void*)rengar_all, dim3(NBLK), dim3(TPB),
                             args, 0, stream);
}